// Round 2
// baseline (487.284 us; speedup 1.0000x reference)
//
#include <hip/hip_runtime.h>
#include <cstdint>

// ---------------------------------------------------------------------------
// AttentionAIC: dual-stream QKV proj + per-head RMSNorm + joint SDPA + out-proj
// B=1, S=2048, S_enc=256, D=1536, H=24, HD=64, T=2304.
// Context output is discarded by the reference -> skip add_q_proj, encoder
// q-rows of attention, and to_add_out entirely.
// R2: flash rewritten — no online max (scores bounded |s|<=8 by Cauchy-Schwarz
// on RMSNormed q,k), row-sums via ones-MFMA, split-K over the 4 waves.
// ---------------------------------------------------------------------------

typedef __attribute__((ext_vector_type(8))) short s16x8;   // 8 x bf16
typedef __attribute__((ext_vector_type(4))) float f32x4;

#define LOG2E 1.4426950408889634f

__device__ __forceinline__ short f2bf(float f) {          // RNE (epilogues)
  union { float f; uint32_t u; } v; v.f = f;
  uint32_t r = v.u + 0x7FFFu + ((v.u >> 16) & 1u);
  return (short)(r >> 16);
}
__device__ __forceinline__ short f2bf_fast(float f) {     // round-to-nearest
  union { float f; uint32_t u; } v; v.f = f;
  return (short)((v.u + 0x8000u) >> 16);
}

typedef uint32_t __attribute__((address_space(1)))* gas_u32;
typedef uint32_t __attribute__((address_space(3)))* las_u32;

// async global->LDS, 16B per lane; dest must be wave-uniform base + lane*16
__device__ __forceinline__ void gload_lds16(const short* g, short* l) {
  __builtin_amdgcn_global_load_lds((gas_u32)(g), (las_u32)(l), 16, 0, 0);
}

// ---------------------------------------------------------------------------
// fp32 -> bf16 conversion (8 segments in one launch)
// ---------------------------------------------------------------------------
struct CvtSeg { const float* src; short* dst; int n4; };
struct CvtArgs { CvtSeg s[8]; };

__global__ __launch_bounds__(256) void cvt_bf16_kernel(CvtArgs a) {
  const int stride = gridDim.x * blockDim.x;
  const int tid = blockIdx.x * blockDim.x + threadIdx.x;
  for (int i = 0; i < 8; ++i) {
    const float4* src = (const float4*)a.s[i].src;
    short* dst = a.s[i].dst;
    const int n4 = a.s[i].n4;
    for (int j = tid; j < n4; j += stride) {
      float4 v = src[j];
      short4 o;
      o.x = f2bf(v.x); o.y = f2bf(v.y); o.z = f2bf(v.z); o.w = f2bf(v.w);
      *(short4*)(dst + (size_t)j * 4) = o;
    }
  }
}

// ---------------------------------------------------------------------------
// GEMM: C[M,1536] = A[M,1536] @ W[1536,1536]^T (+bias) with fused epilogues
// 128x128 tile, BK=32, 4 waves (2x2), wave = 64x64 via 4x4 of 16x16x32 MFMA.
// ---------------------------------------------------------------------------
enum { MODE_Q = 0, MODE_K = 1, MODE_V = 2, MODE_OUT = 3 };

struct GemmCfg {
  const short* A;      // [M,1536] bf16
  const short* W;      // [1536,1536] bf16, row-major [N][K]
  const float* bias;   // [1536] fp32
  const float* normw;  // [64] fp32 (Q/K modes)
  void* dst;
  int toff;            // t offset for K/V (0 hidden, 2048 encoder)
  int mode;
  int mtiles;          // # of 128-row M tiles (16 hidden, 2 encoder)
};
struct GemmArgs { GemmCfg c[5]; };

__global__ __launch_bounds__(256) void proj_gemm_kernel(GemmArgs args) {
  const GemmCfg cfg = args.c[blockIdx.z];
  if ((int)blockIdx.y >= cfg.mtiles) return;
  constexpr int K = 1536;
  __shared__ short As[4096];  // [128][32]
  __shared__ short Bs[4096];  // [128][32]
  const int t = threadIdx.x;
  const int lane = t & 63;
  const int wave = t >> 6;
  const int l16 = lane & 15;
  const int quad = lane >> 4;
  const int wm = wave >> 1;
  const int wn = wave & 1;

  const short* __restrict__ Ag = cfg.A + (size_t)(blockIdx.y * 128) * K;
  const short* __restrict__ Wg = cfg.W + (size_t)(blockIdx.x * 128) * K;
  const int srow = t >> 2;          // 0..63
  const int scol = (t & 3) << 3;    // 0,8,16,24

  const f32x4 z4 = {0.f, 0.f, 0.f, 0.f};
  f32x4 acc[4][4];
#pragma unroll
  for (int i = 0; i < 4; ++i) {
#pragma unroll
    for (int j = 0; j < 4; ++j) acc[i][j] = z4;
  }

  for (int k0 = 0; k0 < K; k0 += 32) {
    gload_lds16(Ag + (size_t)srow * K + k0 + scol, As + t * 8);
    gload_lds16(Ag + (size_t)(srow + 64) * K + k0 + scol, As + 2048 + t * 8);
    gload_lds16(Wg + (size_t)srow * K + k0 + scol, Bs + t * 8);
    gload_lds16(Wg + (size_t)(srow + 64) * K + k0 + scol, Bs + 2048 + t * 8);
    __syncthreads();
    s16x8 af[4], bfr[4];
#pragma unroll
    for (int i = 0; i < 4; ++i)
      af[i] = *(const s16x8*)(As + (wm * 64 + i * 16 + l16) * 32 + quad * 8);
#pragma unroll
    for (int i = 0; i < 4; ++i)
      bfr[i] = *(const s16x8*)(Bs + (wn * 64 + i * 16 + l16) * 32 + quad * 8);
#pragma unroll
    for (int mi = 0; mi < 4; ++mi) {
#pragma unroll
      for (int ni = 0; ni < 4; ++ni)
        acc[mi][ni] = __builtin_amdgcn_mfma_f32_16x16x32_bf16(af[mi], bfr[ni], acc[mi][ni], 0, 0, 0);
    }
    __syncthreads();
  }

  // epilogue: C/D layout col=lane&15, row=quad*4+reg
  const int nbase = blockIdx.x * 128 + wn * 64;   // 64-aligned -> one head/wave
  const int mbase = blockIdx.y * 128 + wm * 64;
  const int mode = cfg.mode;
  const int h = nbase >> 6;

  float biasv[4], nwv[4];
#pragma unroll
  for (int ni = 0; ni < 4; ++ni) {
    int col = nbase + ni * 16 + l16;
    biasv[ni] = cfg.bias[col];
    nwv[ni] = (mode == MODE_Q || mode == MODE_K) ? cfg.normw[col & 63] : 0.f;
  }

#pragma unroll
  for (int mi = 0; mi < 4; ++mi) {
    float vv[4][4];
#pragma unroll
    for (int ni = 0; ni < 4; ++ni) {
#pragma unroll
      for (int r = 0; r < 4; ++r) vv[ni][r] = acc[mi][ni][r] + biasv[ni];
    }
    if (mode == MODE_Q || mode == MODE_K) {
      // RMSNorm over the head (this wave's 64 cols): reduce ni then 16 lanes
      float ss[4];
#pragma unroll
      for (int r = 0; r < 4; ++r)
        ss[r] = vv[0][r] * vv[0][r] + vv[1][r] * vv[1][r] +
                vv[2][r] * vv[2][r] + vv[3][r] * vv[3][r];
#pragma unroll
      for (int r = 0; r < 4; ++r) {
        ss[r] += __shfl_xor(ss[r], 1);
        ss[r] += __shfl_xor(ss[r], 2);
        ss[r] += __shfl_xor(ss[r], 4);
        ss[r] += __shfl_xor(ss[r], 8);
        float rs = rsqrtf(ss[r] * (1.0f / 64.0f) + 1e-6f);
#pragma unroll
        for (int ni = 0; ni < 4; ++ni) vv[ni][r] *= rs * nwv[ni];
      }
    }
    const int row0 = mbase + mi * 16 + quad * 4;  // + r
    if (mode == MODE_Q) {
      short* Qd = (short*)cfg.dst;  // [24][2048][64]
#pragma unroll
      for (int ni = 0; ni < 4; ++ni) {
        int d = ni * 16 + l16;
#pragma unroll
        for (int r = 0; r < 4; ++r)
          Qd[((size_t)h * 2048 + row0 + r) * 64 + d] = f2bf(vv[ni][r]);
      }
    } else if (mode == MODE_K) {
      short* Kd = (short*)cfg.dst;  // [24][2304][64]
#pragma unroll
      for (int ni = 0; ni < 4; ++ni) {
        int d = ni * 16 + l16;
#pragma unroll
        for (int r = 0; r < 4; ++r)
          Kd[((size_t)h * 2304 + cfg.toff + row0 + r) * 64 + d] = f2bf(vv[ni][r]);
      }
    } else if (mode == MODE_V) {
      short* Vd = (short*)cfg.dst;  // V^T: [24][64][2304]
#pragma unroll
      for (int ni = 0; ni < 4; ++ni) {
        int d = ni * 16 + l16;
        short4 o4;
        o4.x = f2bf(vv[ni][0]); o4.y = f2bf(vv[ni][1]);
        o4.z = f2bf(vv[ni][2]); o4.w = f2bf(vv[ni][3]);
        *(short4*)(Vd + ((size_t)h * 64 + d) * 2304 + cfg.toff + row0) = o4;
      }
    } else {  // MODE_OUT: fp32 row-major [2048][1536]
      float* Od = (float*)cfg.dst;
#pragma unroll
      for (int ni = 0; ni < 4; ++ni) {
        int col = nbase + ni * 16 + l16;
#pragma unroll
        for (int r = 0; r < 4; ++r)
          Od[(size_t)(row0 + r) * 1536 + col] = vv[ni][r];
      }
    }
  }
}

// ---------------------------------------------------------------------------
// Flash attention, split-K over waves:
// block = (16 q-rows, head); 4 waves each own 576 of the 2304 k positions.
// No online max: q,k are RMSNormed (||q||=||k||=8) => |score| <= 8; mask
// added raw. l = P @ ones via MFMA (same C-layout as o). Combine partial
// (o,l) across waves through LDS at the end.
// ---------------------------------------------------------------------------
__global__ __launch_bounds__(256, 8) void flash_kernel(
    const short* __restrict__ Q, const short* __restrict__ Kc,
    const short* __restrict__ VT, const float* __restrict__ mask,
    short* __restrict__ AO) {
  const int h = blockIdx.y;
  const int lane = threadIdx.x & 63;
  const int wave = threadIdx.x >> 6;
  const int l16 = lane & 15;
  const int quad = lane >> 4;
  const int q0 = blockIdx.x * 16;

  // 0..8191:  per-wave 16x64 bf16 P tiles (loop phase)
  // 0..16383: RedO (4 waves x 4 ni x 64 lanes f32x4)   (reduce phase)
  // 16384..20479: RedL (4 waves x 64 lanes f32x4)
  __shared__ __align__(16) char smem[20480];
  short* Pw = (short*)smem + wave * 1024;

  const short* Qrow = Q + ((size_t)h * 2048 + q0 + l16) * 64;
  s16x8 aq0 = *(const s16x8*)(Qrow + quad * 8);
  s16x8 aq1 = *(const s16x8*)(Qrow + quad * 8 + 32);

  s16x8 ones;
#pragma unroll
  for (int i = 0; i < 8; ++i) ones[i] = (short)0x3F80;  // bf16 1.0

  const f32x4 z4 = {0.f, 0.f, 0.f, 0.f};
  f32x4 o[4] = {z4, z4, z4, z4};
  f32x4 lacc = z4;

  const short* Kh = Kc + (size_t)h * 2304 * 64;
  const short* Vh = VT + (size_t)h * 64 * 2304;
  const float SC = 0.125f * LOG2E;

  const int kb0 = wave * 576;
  for (int kb = kb0; kb < kb0 + 576; kb += 64) {
#pragma unroll
    for (int ni = 0; ni < 4; ++ni) {
      const short* Krow = Kh + (size_t)(kb + ni * 16 + l16) * 64;
      f32x4 p0 = __builtin_amdgcn_mfma_f32_16x16x32_bf16(
          aq0, *(const s16x8*)(Krow + quad * 8), z4, 0, 0, 0);
      f32x4 s = __builtin_amdgcn_mfma_f32_16x16x32_bf16(
          aq1, *(const s16x8*)(Krow + quad * 8 + 32), p0, 0, 0, 0);
      float mvl = mask[kb + ni * 16 + l16] * LOG2E;
      int pcol = ni * 16 + l16;
      int cb = pcol >> 3;
#pragma unroll
      for (int r = 0; r < 4; ++r) {
        float p = __builtin_amdgcn_exp2f(fmaf(s[r], SC, mvl));
        int prow = quad * 4 + r;
        Pw[prow * 64 + ((cb ^ (prow & 7)) << 3) + (pcol & 7)] = f2bf_fast(p);
      }
    }
    // P: C-layout -> A-operand layout via per-wave LDS (no barrier needed)
    s16x8 ap0 = *(const s16x8*)(Pw + l16 * 64 + ((quad ^ (l16 & 7)) << 3));
    s16x8 ap1 = *(const s16x8*)(Pw + l16 * 64 + (((quad + 4) ^ (l16 & 7)) << 3));
    lacc = __builtin_amdgcn_mfma_f32_16x16x32_bf16(ap0, ones, lacc, 0, 0, 0);
    lacc = __builtin_amdgcn_mfma_f32_16x16x32_bf16(ap1, ones, lacc, 0, 0, 0);
#pragma unroll
    for (int ni = 0; ni < 4; ++ni) {
      const short* Vrow = Vh + (size_t)(ni * 16 + l16) * 2304 + kb;
      o[ni] = __builtin_amdgcn_mfma_f32_16x16x32_bf16(
          ap0, *(const s16x8*)(Vrow + quad * 8), o[ni], 0, 0, 0);
      o[ni] = __builtin_amdgcn_mfma_f32_16x16x32_bf16(
          ap1, *(const s16x8*)(Vrow + quad * 8 + 32), o[ni], 0, 0, 0);
    }
  }

  __syncthreads();                       // all P usage done; recycle smem
  f32x4* RedO = (f32x4*)smem;            // [wave][ni][lane]
  f32x4* RedL = (f32x4*)(smem + 16384);  // [wave][lane]
#pragma unroll
  for (int ni = 0; ni < 4; ++ni) RedO[(wave * 4 + ni) * 64 + lane] = o[ni];
  RedL[wave * 64 + lane] = lacc;
  __syncthreads();

  // wave w combines fragment ni == w across the 4 k-partitions
  f32x4 osum = RedO[(0 * 4 + wave) * 64 + lane];
  f32x4 lsum = RedL[0 * 64 + lane];
#pragma unroll
  for (int w = 1; w < 4; ++w) {
    osum += RedO[(w * 4 + wave) * 64 + lane];
    lsum += RedL[w * 64 + lane];
  }
#pragma unroll
  for (int r = 0; r < 4; ++r) {
    int tq = q0 + quad * 4 + r;
    AO[(size_t)tq * 1536 + h * 64 + wave * 16 + l16] = f2bf(osum[r] / lsum[r]);
  }
}

// ---------------------------------------------------------------------------
extern "C" void kernel_launch(void* const* d_in, const int* in_sizes, int n_in,
                              void* d_out, int out_size, void* d_ws, size_t ws_size,
                              hipStream_t stream) {
  (void)in_sizes; (void)n_in; (void)out_size; (void)ws_size;
  const float* hidden = (const float*)d_in[0];
  const float* enc    = (const float*)d_in[1];
  const float* amask  = (const float*)d_in[2];
  const float* wq  = (const float*)d_in[3];  const float* bq  = (const float*)d_in[4];
  const float* wk  = (const float*)d_in[5];  const float* bk  = (const float*)d_in[6];
  const float* wv  = (const float*)d_in[7];  const float* bv  = (const float*)d_in[8];
  const float* nqw = (const float*)d_in[9];  const float* nkw = (const float*)d_in[10];
  // d_in[11],[12],[17]: add_q_proj + norm_added_q -> dead (context q unused)
  const float* wak = (const float*)d_in[13]; const float* bak = (const float*)d_in[14];
  const float* wav = (const float*)d_in[15]; const float* bav = (const float*)d_in[16];
  const float* nakw = (const float*)d_in[18];
  const float* wo  = (const float*)d_in[19]; const float* bo  = (const float*)d_in[20];
  // d_in[21],[22]: to_add_out -> dead
  float* out = (float*)d_out;

  char* p = (char*)d_ws;
  auto carve = [&](size_t bytes) { char* r = p; p += (bytes + 255) & ~(size_t)255; return r; };
  short* Xb   = (short*)carve((size_t)2048 * 1536 * 2);
  short* Eb   = (short*)carve((size_t)256 * 1536 * 2);
  short* Wqb  = (short*)carve((size_t)1536 * 1536 * 2);
  short* Wkb  = (short*)carve((size_t)1536 * 1536 * 2);
  short* Wvb  = (short*)carve((size_t)1536 * 1536 * 2);
  short* Wakb = (short*)carve((size_t)1536 * 1536 * 2);
  short* Wavb = (short*)carve((size_t)1536 * 1536 * 2);
  short* Wob  = (short*)carve((size_t)1536 * 1536 * 2);
  short* Qb   = (short*)carve((size_t)24 * 2048 * 64 * 2);
  short* Kb   = (short*)carve((size_t)24 * 2304 * 64 * 2);
  short* VTb  = (short*)carve((size_t)24 * 64 * 2304 * 2);
  short* AOb  = (short*)carve((size_t)2048 * 1536 * 2);

  CvtArgs ca;
  ca.s[0] = {hidden, Xb, 2048 * 1536 / 4};
  ca.s[1] = {enc,    Eb, 256 * 1536 / 4};
  ca.s[2] = {wq,  Wqb,  1536 * 1536 / 4};
  ca.s[3] = {wk,  Wkb,  1536 * 1536 / 4};
  ca.s[4] = {wv,  Wvb,  1536 * 1536 / 4};
  ca.s[5] = {wak, Wakb, 1536 * 1536 / 4};
  ca.s[6] = {wav, Wavb, 1536 * 1536 / 4};
  ca.s[7] = {wo,  Wob,  1536 * 1536 / 4};
  cvt_bf16_kernel<<<dim3(1024), dim3(256), 0, stream>>>(ca);

  GemmArgs g1;  // all five projections in one launch (z = 0..4)
  g1.c[0] = {Xb, Wqb,  bq,  nqw,     (void*)Qb,  0,    MODE_Q, 16};
  g1.c[1] = {Xb, Wkb,  bk,  nkw,     (void*)Kb,  0,    MODE_K, 16};
  g1.c[2] = {Xb, Wvb,  bv,  nullptr, (void*)VTb, 0,    MODE_V, 16};
  g1.c[3] = {Eb, Wakb, bak, nakw,    (void*)Kb,  2048, MODE_K, 2};
  g1.c[4] = {Eb, Wavb, bav, nullptr, (void*)VTb, 2048, MODE_V, 2};
  proj_gemm_kernel<<<dim3(12, 16, 5), dim3(256), 0, stream>>>(g1);

  flash_kernel<<<dim3(128, 24), dim3(256), 0, stream>>>(Qb, Kb, VTb, amask, AOb);

  GemmArgs g3;  // out projection -> fp32 d_out
  g3.c[0] = {AOb, Wob, bo, nullptr, (void*)out, 0, MODE_OUT, 16};
  proj_gemm_kernel<<<dim3(12, 16, 1), dim3(256), 0, stream>>>(g3);
}

// Round 3
// 434.348 us; speedup vs baseline: 1.1219x; 1.1219x over previous
//
#include <hip/hip_runtime.h>
#include <cstdint>

// ---------------------------------------------------------------------------
// AttentionAIC: dual-stream QKV proj + per-head RMSNorm + joint SDPA + out-proj
// B=1, S=2048, S_enc=256, D=1536, H=24, HD=64, T=2304.
// Context output is discarded by the reference -> skip add_q_proj, encoder
// q-rows of attention, and to_add_out entirely.
// R3: fix R2's scratch-spill regression (launch_bounds(256,8) forced VGPR=32,
// +33MB WRITE_SIZE of spills). Plain launch_bounds(256) -> ~60 VGPR, no spill.
// Also XCD-aware block swizzle so each XCD's L2 holds only 3 heads of K/V.
// ---------------------------------------------------------------------------

typedef __attribute__((ext_vector_type(8))) short s16x8;   // 8 x bf16
typedef __attribute__((ext_vector_type(4))) float f32x4;

#define LOG2E 1.4426950408889634f

__device__ __forceinline__ short f2bf(float f) {          // RNE (epilogues)
  union { float f; uint32_t u; } v; v.f = f;
  uint32_t r = v.u + 0x7FFFu + ((v.u >> 16) & 1u);
  return (short)(r >> 16);
}
__device__ __forceinline__ short f2bf_fast(float f) {     // round-to-nearest
  union { float f; uint32_t u; } v; v.f = f;
  return (short)((v.u + 0x8000u) >> 16);
}

typedef uint32_t __attribute__((address_space(1)))* gas_u32;
typedef uint32_t __attribute__((address_space(3)))* las_u32;

// async global->LDS, 16B per lane; dest must be wave-uniform base + lane*16
__device__ __forceinline__ void gload_lds16(const short* g, short* l) {
  __builtin_amdgcn_global_load_lds((gas_u32)(g), (las_u32)(l), 16, 0, 0);
}

// ---------------------------------------------------------------------------
// fp32 -> bf16 conversion (8 segments in one launch)
// ---------------------------------------------------------------------------
struct CvtSeg { const float* src; short* dst; int n4; };
struct CvtArgs { CvtSeg s[8]; };

__global__ __launch_bounds__(256) void cvt_bf16_kernel(CvtArgs a) {
  const int stride = gridDim.x * blockDim.x;
  const int tid = blockIdx.x * blockDim.x + threadIdx.x;
  for (int i = 0; i < 8; ++i) {
    const float4* src = (const float4*)a.s[i].src;
    short* dst = a.s[i].dst;
    const int n4 = a.s[i].n4;
    for (int j = tid; j < n4; j += stride) {
      float4 v = src[j];
      short4 o;
      o.x = f2bf(v.x); o.y = f2bf(v.y); o.z = f2bf(v.z); o.w = f2bf(v.w);
      *(short4*)(dst + (size_t)j * 4) = o;
    }
  }
}

// ---------------------------------------------------------------------------
// GEMM: C[M,1536] = A[M,1536] @ W[1536,1536]^T (+bias) with fused epilogues
// 128x128 tile, BK=32, 4 waves (2x2), wave = 64x64 via 4x4 of 16x16x32 MFMA.
// ---------------------------------------------------------------------------
enum { MODE_Q = 0, MODE_K = 1, MODE_V = 2, MODE_OUT = 3 };

struct GemmCfg {
  const short* A;      // [M,1536] bf16
  const short* W;      // [1536,1536] bf16, row-major [N][K]
  const float* bias;   // [1536] fp32
  const float* normw;  // [64] fp32 (Q/K modes)
  void* dst;
  int toff;            // t offset for K/V (0 hidden, 2048 encoder)
  int mode;
  int mtiles;          // # of 128-row M tiles (16 hidden, 2 encoder)
};
struct GemmArgs { GemmCfg c[5]; };

__global__ __launch_bounds__(256) void proj_gemm_kernel(GemmArgs args) {
  const GemmCfg cfg = args.c[blockIdx.z];
  if ((int)blockIdx.y >= cfg.mtiles) return;
  constexpr int K = 1536;
  __shared__ short As[4096];  // [128][32]
  __shared__ short Bs[4096];  // [128][32]
  const int t = threadIdx.x;
  const int lane = t & 63;
  const int wave = t >> 6;
  const int l16 = lane & 15;
  const int quad = lane >> 4;
  const int wm = wave >> 1;
  const int wn = wave & 1;

  const short* __restrict__ Ag = cfg.A + (size_t)(blockIdx.y * 128) * K;
  const short* __restrict__ Wg = cfg.W + (size_t)(blockIdx.x * 128) * K;
  const int srow = t >> 2;          // 0..63
  const int scol = (t & 3) << 3;    // 0,8,16,24

  const f32x4 z4 = {0.f, 0.f, 0.f, 0.f};
  f32x4 acc[4][4];
#pragma unroll
  for (int i = 0; i < 4; ++i) {
#pragma unroll
    for (int j = 0; j < 4; ++j) acc[i][j] = z4;
  }

  for (int k0 = 0; k0 < K; k0 += 32) {
    gload_lds16(Ag + (size_t)srow * K + k0 + scol, As + t * 8);
    gload_lds16(Ag + (size_t)(srow + 64) * K + k0 + scol, As + 2048 + t * 8);
    gload_lds16(Wg + (size_t)srow * K + k0 + scol, Bs + t * 8);
    gload_lds16(Wg + (size_t)(srow + 64) * K + k0 + scol, Bs + 2048 + t * 8);
    __syncthreads();
    s16x8 af[4], bfr[4];
#pragma unroll
    for (int i = 0; i < 4; ++i)
      af[i] = *(const s16x8*)(As + (wm * 64 + i * 16 + l16) * 32 + quad * 8);
#pragma unroll
    for (int i = 0; i < 4; ++i)
      bfr[i] = *(const s16x8*)(Bs + (wn * 64 + i * 16 + l16) * 32 + quad * 8);
#pragma unroll
    for (int mi = 0; mi < 4; ++mi) {
#pragma unroll
      for (int ni = 0; ni < 4; ++ni)
        acc[mi][ni] = __builtin_amdgcn_mfma_f32_16x16x32_bf16(af[mi], bfr[ni], acc[mi][ni], 0, 0, 0);
    }
    __syncthreads();
  }

  // epilogue: C/D layout col=lane&15, row=quad*4+reg
  const int nbase = blockIdx.x * 128 + wn * 64;   // 64-aligned -> one head/wave
  const int mbase = blockIdx.y * 128 + wm * 64;
  const int mode = cfg.mode;
  const int h = nbase >> 6;

  float biasv[4], nwv[4];
#pragma unroll
  for (int ni = 0; ni < 4; ++ni) {
    int col = nbase + ni * 16 + l16;
    biasv[ni] = cfg.bias[col];
    nwv[ni] = (mode == MODE_Q || mode == MODE_K) ? cfg.normw[col & 63] : 0.f;
  }

#pragma unroll
  for (int mi = 0; mi < 4; ++mi) {
    float vv[4][4];
#pragma unroll
    for (int ni = 0; ni < 4; ++ni) {
#pragma unroll
      for (int r = 0; r < 4; ++r) vv[ni][r] = acc[mi][ni][r] + biasv[ni];
    }
    if (mode == MODE_Q || mode == MODE_K) {
      // RMSNorm over the head (this wave's 64 cols): reduce ni then 16 lanes
      float ss[4];
#pragma unroll
      for (int r = 0; r < 4; ++r)
        ss[r] = vv[0][r] * vv[0][r] + vv[1][r] * vv[1][r] +
                vv[2][r] * vv[2][r] + vv[3][r] * vv[3][r];
#pragma unroll
      for (int r = 0; r < 4; ++r) {
        ss[r] += __shfl_xor(ss[r], 1);
        ss[r] += __shfl_xor(ss[r], 2);
        ss[r] += __shfl_xor(ss[r], 4);
        ss[r] += __shfl_xor(ss[r], 8);
        float rs = rsqrtf(ss[r] * (1.0f / 64.0f) + 1e-6f);
#pragma unroll
        for (int ni = 0; ni < 4; ++ni) vv[ni][r] *= rs * nwv[ni];
      }
    }
    const int row0 = mbase + mi * 16 + quad * 4;  // + r
    if (mode == MODE_Q) {
      short* Qd = (short*)cfg.dst;  // [24][2048][64]
#pragma unroll
      for (int ni = 0; ni < 4; ++ni) {
        int d = ni * 16 + l16;
#pragma unroll
        for (int r = 0; r < 4; ++r)
          Qd[((size_t)h * 2048 + row0 + r) * 64 + d] = f2bf(vv[ni][r]);
      }
    } else if (mode == MODE_K) {
      short* Kd = (short*)cfg.dst;  // [24][2304][64]
#pragma unroll
      for (int ni = 0; ni < 4; ++ni) {
        int d = ni * 16 + l16;
#pragma unroll
        for (int r = 0; r < 4; ++r)
          Kd[((size_t)h * 2304 + cfg.toff + row0 + r) * 64 + d] = f2bf(vv[ni][r]);
      }
    } else if (mode == MODE_V) {
      short* Vd = (short*)cfg.dst;  // V^T: [24][64][2304]
#pragma unroll
      for (int ni = 0; ni < 4; ++ni) {
        int d = ni * 16 + l16;
        short4 o4;
        o4.x = f2bf(vv[ni][0]); o4.y = f2bf(vv[ni][1]);
        o4.z = f2bf(vv[ni][2]); o4.w = f2bf(vv[ni][3]);
        *(short4*)(Vd + ((size_t)h * 64 + d) * 2304 + cfg.toff + row0) = o4;
      }
    } else {  // MODE_OUT: fp32 row-major [2048][1536]
      float* Od = (float*)cfg.dst;
#pragma unroll
      for (int ni = 0; ni < 4; ++ni) {
        int col = nbase + ni * 16 + l16;
#pragma unroll
        for (int r = 0; r < 4; ++r)
          Od[(size_t)(row0 + r) * 1536 + col] = vv[ni][r];
      }
    }
  }
}

// ---------------------------------------------------------------------------
// Flash attention, split-K over waves:
// block = (16 q-rows, head); 4 waves each own 576 of the 2304 k positions.
// No online max: q,k are RMSNormed (||q||=||k||=8) => |score| <= 8; mask
// added raw. l = P @ ones via MFMA (same C-layout as o). Combine partial
// (o,l) across waves through LDS at the end.
// Grid is 1-D (3072) with an XCD swizzle: blocks land on XCD (b&7) round-
// robin, so head = (b&7)*3 + ((b>>3)%3) keeps each XCD's L2 working set to
// 3 heads of K/V (~1.8MB < 4MB). Perf heuristic only, correctness-neutral.
// ---------------------------------------------------------------------------
__global__ __launch_bounds__(256) void flash_kernel(
    const short* __restrict__ Q, const short* __restrict__ Kc,
    const short* __restrict__ VT, const float* __restrict__ mask,
    short* __restrict__ AO) {
  const int b = blockIdx.x;
  const int h = (b & 7) * 3 + ((b >> 3) % 3);
  const int q0 = ((b >> 3) / 3) * 16;
  const int lane = threadIdx.x & 63;
  const int wave = threadIdx.x >> 6;
  const int l16 = lane & 15;
  const int quad = lane >> 4;

  // 0..8191:  per-wave 16x64 bf16 P tiles (loop phase)
  // 0..16383: RedO (4 waves x 4 ni x 64 lanes f32x4)   (reduce phase)
  // 16384..20479: RedL (4 waves x 64 lanes f32x4)
  __shared__ __align__(16) char smem[20480];
  short* Pw = (short*)smem + wave * 1024;

  const short* Qrow = Q + ((size_t)h * 2048 + q0 + l16) * 64;
  s16x8 aq0 = *(const s16x8*)(Qrow + quad * 8);
  s16x8 aq1 = *(const s16x8*)(Qrow + quad * 8 + 32);

  s16x8 ones;
#pragma unroll
  for (int i = 0; i < 8; ++i) ones[i] = (short)0x3F80;  // bf16 1.0

  const f32x4 z4 = {0.f, 0.f, 0.f, 0.f};
  f32x4 o[4] = {z4, z4, z4, z4};
  f32x4 lacc = z4;

  const short* Kh = Kc + (size_t)h * 2304 * 64;
  const short* Vh = VT + (size_t)h * 64 * 2304;
  const float SC = 0.125f * LOG2E;

  const int kb0 = wave * 576;
  for (int kb = kb0; kb < kb0 + 576; kb += 64) {
#pragma unroll
    for (int ni = 0; ni < 4; ++ni) {
      const short* Krow = Kh + (size_t)(kb + ni * 16 + l16) * 64;
      f32x4 p0 = __builtin_amdgcn_mfma_f32_16x16x32_bf16(
          aq0, *(const s16x8*)(Krow + quad * 8), z4, 0, 0, 0);
      f32x4 s = __builtin_amdgcn_mfma_f32_16x16x32_bf16(
          aq1, *(const s16x8*)(Krow + quad * 8 + 32), p0, 0, 0, 0);
      float mvl = mask[kb + ni * 16 + l16] * LOG2E;
      int pcol = ni * 16 + l16;
      int cb = pcol >> 3;
#pragma unroll
      for (int r = 0; r < 4; ++r) {
        float p = __builtin_amdgcn_exp2f(fmaf(s[r], SC, mvl));
        int prow = quad * 4 + r;
        Pw[prow * 64 + ((cb ^ (prow & 7)) << 3) + (pcol & 7)] = f2bf_fast(p);
      }
    }
    // P: C-layout -> A-operand layout via per-wave LDS (no barrier needed)
    s16x8 ap0 = *(const s16x8*)(Pw + l16 * 64 + ((quad ^ (l16 & 7)) << 3));
    s16x8 ap1 = *(const s16x8*)(Pw + l16 * 64 + (((quad + 4) ^ (l16 & 7)) << 3));
    lacc = __builtin_amdgcn_mfma_f32_16x16x32_bf16(ap0, ones, lacc, 0, 0, 0);
    lacc = __builtin_amdgcn_mfma_f32_16x16x32_bf16(ap1, ones, lacc, 0, 0, 0);
#pragma unroll
    for (int ni = 0; ni < 4; ++ni) {
      const short* Vrow = Vh + (size_t)(ni * 16 + l16) * 2304 + kb;
      o[ni] = __builtin_amdgcn_mfma_f32_16x16x32_bf16(
          ap0, *(const s16x8*)(Vrow + quad * 8), o[ni], 0, 0, 0);
      o[ni] = __builtin_amdgcn_mfma_f32_16x16x32_bf16(
          ap1, *(const s16x8*)(Vrow + quad * 8 + 32), o[ni], 0, 0, 0);
    }
  }

  __syncthreads();                       // all P usage done; recycle smem
  f32x4* RedO = (f32x4*)smem;            // [wave][ni][lane]
  f32x4* RedL = (f32x4*)(smem + 16384);  // [wave][lane]
#pragma unroll
  for (int ni = 0; ni < 4; ++ni) RedO[(wave * 4 + ni) * 64 + lane] = o[ni];
  RedL[wave * 64 + lane] = lacc;
  __syncthreads();

  // wave w combines fragment ni == w across the 4 k-partitions
  f32x4 osum = RedO[(0 * 4 + wave) * 64 + lane];
  f32x4 lsum = RedL[0 * 64 + lane];
#pragma unroll
  for (int w = 1; w < 4; ++w) {
    osum += RedO[(w * 4 + wave) * 64 + lane];
    lsum += RedL[w * 64 + lane];
  }
#pragma unroll
  for (int r = 0; r < 4; ++r) {
    int tq = q0 + quad * 4 + r;
    AO[(size_t)tq * 1536 + h * 64 + wave * 16 + l16] = f2bf(osum[r] / lsum[r]);
  }
}

// ---------------------------------------------------------------------------
extern "C" void kernel_launch(void* const* d_in, const int* in_sizes, int n_in,
                              void* d_out, int out_size, void* d_ws, size_t ws_size,
                              hipStream_t stream) {
  (void)in_sizes; (void)n_in; (void)out_size; (void)ws_size;
  const float* hidden = (const float*)d_in[0];
  const float* enc    = (const float*)d_in[1];
  const float* amask  = (const float*)d_in[2];
  const float* wq  = (const float*)d_in[3];  const float* bq  = (const float*)d_in[4];
  const float* wk  = (const float*)d_in[5];  const float* bk  = (const float*)d_in[6];
  const float* wv  = (const float*)d_in[7];  const float* bv  = (const float*)d_in[8];
  const float* nqw = (const float*)d_in[9];  const float* nkw = (const float*)d_in[10];
  // d_in[11],[12],[17]: add_q_proj + norm_added_q -> dead (context q unused)
  const float* wak = (const float*)d_in[13]; const float* bak = (const float*)d_in[14];
  const float* wav = (const float*)d_in[15]; const float* bav = (const float*)d_in[16];
  const float* nakw = (const float*)d_in[18];
  const float* wo  = (const float*)d_in[19]; const float* bo  = (const float*)d_in[20];
  // d_in[21],[22]: to_add_out -> dead
  float* out = (float*)d_out;

  char* p = (char*)d_ws;
  auto carve = [&](size_t bytes) { char* r = p; p += (bytes + 255) & ~(size_t)255; return r; };
  short* Xb   = (short*)carve((size_t)2048 * 1536 * 2);
  short* Eb   = (short*)carve((size_t)256 * 1536 * 2);
  short* Wqb  = (short*)carve((size_t)1536 * 1536 * 2);
  short* Wkb  = (short*)carve((size_t)1536 * 1536 * 2);
  short* Wvb  = (short*)carve((size_t)1536 * 1536 * 2);
  short* Wakb = (short*)carve((size_t)1536 * 1536 * 2);
  short* Wavb = (short*)carve((size_t)1536 * 1536 * 2);
  short* Wob  = (short*)carve((size_t)1536 * 1536 * 2);
  short* Qb   = (short*)carve((size_t)24 * 2048 * 64 * 2);
  short* Kb   = (short*)carve((size_t)24 * 2304 * 64 * 2);
  short* VTb  = (short*)carve((size_t)24 * 64 * 2304 * 2);
  short* AOb  = (short*)carve((size_t)2048 * 1536 * 2);

  CvtArgs ca;
  ca.s[0] = {hidden, Xb, 2048 * 1536 / 4};
  ca.s[1] = {enc,    Eb, 256 * 1536 / 4};
  ca.s[2] = {wq,  Wqb,  1536 * 1536 / 4};
  ca.s[3] = {wk,  Wkb,  1536 * 1536 / 4};
  ca.s[4] = {wv,  Wvb,  1536 * 1536 / 4};
  ca.s[5] = {wak, Wakb, 1536 * 1536 / 4};
  ca.s[6] = {wav, Wavb, 1536 * 1536 / 4};
  ca.s[7] = {wo,  Wob,  1536 * 1536 / 4};
  cvt_bf16_kernel<<<dim3(1024), dim3(256), 0, stream>>>(ca);

  GemmArgs g1;  // all five projections in one launch (z = 0..4)
  g1.c[0] = {Xb, Wqb,  bq,  nqw,     (void*)Qb,  0,    MODE_Q, 16};
  g1.c[1] = {Xb, Wkb,  bk,  nkw,     (void*)Kb,  0,    MODE_K, 16};
  g1.c[2] = {Xb, Wvb,  bv,  nullptr, (void*)VTb, 0,    MODE_V, 16};
  g1.c[3] = {Eb, Wakb, bak, nakw,    (void*)Kb,  2048, MODE_K, 2};
  g1.c[4] = {Eb, Wavb, bav, nullptr, (void*)VTb, 2048, MODE_V, 2};
  proj_gemm_kernel<<<dim3(12, 16, 5), dim3(256), 0, stream>>>(g1);

  flash_kernel<<<dim3(3072), dim3(256), 0, stream>>>(Qb, Kb, VTb, amask, AOb);

  GemmArgs g3;  // out projection -> fp32 d_out
  g3.c[0] = {AOb, Wob, bo, nullptr, (void*)out, 0, MODE_OUT, 16};
  proj_gemm_kernel<<<dim3(12, 16, 1), dim3(256), 0, stream>>>(g3);
}

// Round 4
// 303.985 us; speedup vs baseline: 1.6030x; 1.4288x over previous
//
#include <hip/hip_runtime.h>
#include <cstdint>

// ---------------------------------------------------------------------------
// AttentionAIC: dual-stream QKV proj + per-head RMSNorm + joint SDPA + out-proj
// B=1, S=2048, S_enc=256, D=1536, H=24, HD=64, T=2304.
// Context output discarded by the reference -> skip add_q_proj, encoder q-rows
// of attention, and to_add_out.
// R4: flash restructured. R3 was latency-bound (MfmaUtil 6%, VALU 15%, HBM 1%):
// 17 scattered global loads/iter serialized into VGPRs. Now: 64-q blocks, the
// 4 waves share K/V tiles staged via async global_load_lds into double-buffered
// LDS, ONE barrier per tile (stage-next -> compute-cur -> barrier), XOR-chunk
// source swizzle to kill the 128B-stride bank conflict (global_load_lds can't
// pad). No split-K -> no final reduction.
// ---------------------------------------------------------------------------

typedef __attribute__((ext_vector_type(8))) short s16x8;   // 8 x bf16
typedef __attribute__((ext_vector_type(4))) float f32x4;

#define LOG2E 1.4426950408889634f

__device__ __forceinline__ short f2bf(float f) {          // RNE (epilogues)
  union { float f; uint32_t u; } v; v.f = f;
  uint32_t r = v.u + 0x7FFFu + ((v.u >> 16) & 1u);
  return (short)(r >> 16);
}
__device__ __forceinline__ short f2bf_fast(float f) {     // round-to-nearest
  union { float f; uint32_t u; } v; v.f = f;
  return (short)((v.u + 0x8000u) >> 16);
}

typedef uint32_t __attribute__((address_space(1)))* gas_u32;
typedef uint32_t __attribute__((address_space(3)))* las_u32;

// async global->LDS, 16B per lane; dest must be wave-uniform base + lane*16
__device__ __forceinline__ void gload_lds16(const short* g, short* l) {
  __builtin_amdgcn_global_load_lds((gas_u32)(g), (las_u32)(l), 16, 0, 0);
}

// ---------------------------------------------------------------------------
// fp32 -> bf16 conversion (8 segments in one launch)
// ---------------------------------------------------------------------------
struct CvtSeg { const float* src; short* dst; int n4; };
struct CvtArgs { CvtSeg s[8]; };

__global__ __launch_bounds__(256) void cvt_bf16_kernel(CvtArgs a) {
  const int stride = gridDim.x * blockDim.x;
  const int tid = blockIdx.x * blockDim.x + threadIdx.x;
  for (int i = 0; i < 8; ++i) {
    const float4* src = (const float4*)a.s[i].src;
    short* dst = a.s[i].dst;
    const int n4 = a.s[i].n4;
    for (int j = tid; j < n4; j += stride) {
      float4 v = src[j];
      short4 o;
      o.x = f2bf(v.x); o.y = f2bf(v.y); o.z = f2bf(v.z); o.w = f2bf(v.w);
      *(short4*)(dst + (size_t)j * 4) = o;
    }
  }
}

// ---------------------------------------------------------------------------
// GEMM: C[M,1536] = A[M,1536] @ W[1536,1536]^T (+bias) with fused epilogues
// 128x128 tile, BK=32, 4 waves (2x2), wave = 64x64 via 4x4 of 16x16x32 MFMA.
// ---------------------------------------------------------------------------
enum { MODE_Q = 0, MODE_K = 1, MODE_V = 2, MODE_OUT = 3 };

struct GemmCfg {
  const short* A;      // [M,1536] bf16
  const short* W;      // [1536,1536] bf16, row-major [N][K]
  const float* bias;   // [1536] fp32
  const float* normw;  // [64] fp32 (Q/K modes)
  void* dst;
  int toff;            // t offset for K/V (0 hidden, 2048 encoder)
  int mode;
  int mtiles;          // # of 128-row M tiles (16 hidden, 2 encoder)
};
struct GemmArgs { GemmCfg c[5]; };

__global__ __launch_bounds__(256) void proj_gemm_kernel(GemmArgs args) {
  const GemmCfg cfg = args.c[blockIdx.z];
  if ((int)blockIdx.y >= cfg.mtiles) return;
  constexpr int K = 1536;
  __shared__ short As[4096];  // [128][32]
  __shared__ short Bs[4096];  // [128][32]
  const int t = threadIdx.x;
  const int lane = t & 63;
  const int wave = t >> 6;
  const int l16 = lane & 15;
  const int quad = lane >> 4;
  const int wm = wave >> 1;
  const int wn = wave & 1;

  const short* __restrict__ Ag = cfg.A + (size_t)(blockIdx.y * 128) * K;
  const short* __restrict__ Wg = cfg.W + (size_t)(blockIdx.x * 128) * K;
  const int srow = t >> 2;          // 0..63
  const int scol = (t & 3) << 3;    // 0,8,16,24

  const f32x4 z4 = {0.f, 0.f, 0.f, 0.f};
  f32x4 acc[4][4];
#pragma unroll
  for (int i = 0; i < 4; ++i) {
#pragma unroll
    for (int j = 0; j < 4; ++j) acc[i][j] = z4;
  }

  for (int k0 = 0; k0 < K; k0 += 32) {
    gload_lds16(Ag + (size_t)srow * K + k0 + scol, As + t * 8);
    gload_lds16(Ag + (size_t)(srow + 64) * K + k0 + scol, As + 2048 + t * 8);
    gload_lds16(Wg + (size_t)srow * K + k0 + scol, Bs + t * 8);
    gload_lds16(Wg + (size_t)(srow + 64) * K + k0 + scol, Bs + 2048 + t * 8);
    __syncthreads();
    s16x8 af[4], bfr[4];
#pragma unroll
    for (int i = 0; i < 4; ++i)
      af[i] = *(const s16x8*)(As + (wm * 64 + i * 16 + l16) * 32 + quad * 8);
#pragma unroll
    for (int i = 0; i < 4; ++i)
      bfr[i] = *(const s16x8*)(Bs + (wn * 64 + i * 16 + l16) * 32 + quad * 8);
#pragma unroll
    for (int mi = 0; mi < 4; ++mi) {
#pragma unroll
      for (int ni = 0; ni < 4; ++ni)
        acc[mi][ni] = __builtin_amdgcn_mfma_f32_16x16x32_bf16(af[mi], bfr[ni], acc[mi][ni], 0, 0, 0);
    }
    __syncthreads();
  }

  // epilogue: C/D layout col=lane&15, row=quad*4+reg
  const int nbase = blockIdx.x * 128 + wn * 64;   // 64-aligned -> one head/wave
  const int mbase = blockIdx.y * 128 + wm * 64;
  const int mode = cfg.mode;
  const int h = nbase >> 6;

  float biasv[4], nwv[4];
#pragma unroll
  for (int ni = 0; ni < 4; ++ni) {
    int col = nbase + ni * 16 + l16;
    biasv[ni] = cfg.bias[col];
    nwv[ni] = (mode == MODE_Q || mode == MODE_K) ? cfg.normw[col & 63] : 0.f;
  }

#pragma unroll
  for (int mi = 0; mi < 4; ++mi) {
    float vv[4][4];
#pragma unroll
    for (int ni = 0; ni < 4; ++ni) {
#pragma unroll
      for (int r = 0; r < 4; ++r) vv[ni][r] = acc[mi][ni][r] + biasv[ni];
    }
    if (mode == MODE_Q || mode == MODE_K) {
      // RMSNorm over the head (this wave's 64 cols): reduce ni then 16 lanes
      float ss[4];
#pragma unroll
      for (int r = 0; r < 4; ++r)
        ss[r] = vv[0][r] * vv[0][r] + vv[1][r] * vv[1][r] +
                vv[2][r] * vv[2][r] + vv[3][r] * vv[3][r];
#pragma unroll
      for (int r = 0; r < 4; ++r) {
        ss[r] += __shfl_xor(ss[r], 1);
        ss[r] += __shfl_xor(ss[r], 2);
        ss[r] += __shfl_xor(ss[r], 4);
        ss[r] += __shfl_xor(ss[r], 8);
        float rs = rsqrtf(ss[r] * (1.0f / 64.0f) + 1e-6f);
#pragma unroll
        for (int ni = 0; ni < 4; ++ni) vv[ni][r] *= rs * nwv[ni];
      }
    }
    const int row0 = mbase + mi * 16 + quad * 4;  // + r
    if (mode == MODE_Q) {
      short* Qd = (short*)cfg.dst;  // [24][2048][64]
#pragma unroll
      for (int ni = 0; ni < 4; ++ni) {
        int d = ni * 16 + l16;
#pragma unroll
        for (int r = 0; r < 4; ++r)
          Qd[((size_t)h * 2048 + row0 + r) * 64 + d] = f2bf(vv[ni][r]);
      }
    } else if (mode == MODE_K) {
      short* Kd = (short*)cfg.dst;  // [24][2304][64]
#pragma unroll
      for (int ni = 0; ni < 4; ++ni) {
        int d = ni * 16 + l16;
#pragma unroll
        for (int r = 0; r < 4; ++r)
          Kd[((size_t)h * 2304 + cfg.toff + row0 + r) * 64 + d] = f2bf(vv[ni][r]);
      }
    } else if (mode == MODE_V) {
      short* Vd = (short*)cfg.dst;  // V^T: [24][64][2304]
#pragma unroll
      for (int ni = 0; ni < 4; ++ni) {
        int d = ni * 16 + l16;
        short4 o4;
        o4.x = f2bf(vv[ni][0]); o4.y = f2bf(vv[ni][1]);
        o4.z = f2bf(vv[ni][2]); o4.w = f2bf(vv[ni][3]);
        *(short4*)(Vd + ((size_t)h * 64 + d) * 2304 + cfg.toff + row0) = o4;
      }
    } else {  // MODE_OUT: fp32 row-major [2048][1536]
      float* Od = (float*)cfg.dst;
#pragma unroll
      for (int ni = 0; ni < 4; ++ni) {
        int col = nbase + ni * 16 + l16;
#pragma unroll
        for (int r = 0; r < 4; ++r)
          Od[(size_t)(row0 + r) * 1536 + col] = vv[ni][r];
      }
    }
  }
}

// ---------------------------------------------------------------------------
// Flash attention v3: block = (64 q-rows, head), 4 waves each own 16 q-rows
// across the full 2304-k sweep. K/V 64x64 tiles staged cooperatively with
// async global_load_lds into double-buffered LDS; one barrier per tile.
// Tiles are XOR-chunk-swizzled at the staging SOURCE address (dest must be
// lane-contiguous), so b128 fragment reads are conflict-free despite the
// 128-B row stride. No online max (|score|<=8: RMSNormed q,k); l = P@ones.
// Grid 768 = 8 XCD * 3 heads * 32 qblk, XCD round-robin swizzle.
// ---------------------------------------------------------------------------
__global__ __launch_bounds__(256) void flash_kernel(
    const short* __restrict__ Q, const short* __restrict__ Kc,
    const short* __restrict__ VT, const float* __restrict__ mask,
    short* __restrict__ AO) {
  const int b = blockIdx.x;
  const int h = (b & 7) * 3 + ((b >> 3) % 3);
  const int q0 = ((b >> 3) / 3) * 64;
  const int lane = threadIdx.x & 63;
  const int wave = threadIdx.x >> 6;
  const int l16 = lane & 15;
  const int quad = lane >> 4;

  // LDS: Kt dbuf 2*8KB, Vt dbuf 2*8KB, P 4 waves * 2KB  => 40 KB
  __shared__ __align__(16) short smem[20480];
  short* Pw = smem + 16384 + wave * 1024;

  const short* Kh = Kc + (size_t)h * 2304 * 64;
  const short* Vh = VT + (size_t)h * 64 * 2304;

  // Q fragments: this wave's 16 rows
  const short* Qrow = Q + ((size_t)h * 2048 + q0 + wave * 16 + l16) * 64;
  s16x8 aq0 = *(const s16x8*)(Qrow + quad * 8);
  s16x8 aq1 = *(const s16x8*)(Qrow + quad * 8 + 32);

  s16x8 ones;
#pragma unroll
  for (int i = 0; i < 8; ++i) ones[i] = (short)0x3F80;  // bf16 1.0

  const f32x4 z4 = {0.f, 0.f, 0.f, 0.f};
  f32x4 o[4] = {z4, z4, z4, z4};
  f32x4 lacc = z4;
  const float SC = 0.125f * LOG2E;

  // staging source offsets: lane covers row (wave*16 + srow [+8]), source
  // chunk schunk = (lane&7) ^ (srow&7) so LDS position (lane&7) holds the
  // swizzled chunk. Coalescing unaffected (per-row permutation of 128B).
  const int srow = lane >> 3;                   // 0..7
  const int schunk = (lane & 7) ^ srow;         // srow&7 == srow

  auto stage = [&](int kb, int buf) {
    const short* kg = Kh + (size_t)(kb + wave * 16) * 64;
    short* kt = smem + buf * 4096 + wave * 1024;
    gload_lds16(kg + srow * 64 + schunk * 8, kt + lane * 8);
    gload_lds16(kg + (srow + 8) * 64 + schunk * 8, kt + 512 + lane * 8);
    const short* vg = Vh + (size_t)(wave * 16 + srow) * 2304 + kb;
    short* vt = smem + 8192 + buf * 4096 + wave * 1024;
    gload_lds16(vg + schunk * 8, vt + lane * 8);
    gload_lds16(vg + (size_t)8 * 2304 + schunk * 8, vt + 512 + lane * 8);
  };

  stage(0, 0);
  __syncthreads();

  for (int it = 0; it < 36; ++it) {
    const int buf = it & 1;
    if (it < 35) stage((it + 1) * 64, buf ^ 1);
    const short* kt = smem + buf * 4096;
    const short* vt = smem + 8192 + buf * 4096;
    const int kb = it * 64;

    // QK^T -> exp -> P (per-wave swizzled LDS tile)
#pragma unroll
    for (int ni = 0; ni < 4; ++ni) {
      const int r = ni * 16 + l16;
      const short* kr = kt + r * 64;
      s16x8 bk0 = *(const s16x8*)(kr + ((quad ^ (r & 7)) << 3));
      s16x8 bk1 = *(const s16x8*)(kr + (((quad + 4) ^ (r & 7)) << 3));
      f32x4 p0 = __builtin_amdgcn_mfma_f32_16x16x32_bf16(aq0, bk0, z4, 0, 0, 0);
      f32x4 s  = __builtin_amdgcn_mfma_f32_16x16x32_bf16(aq1, bk1, p0, 0, 0, 0);
      float mvl = mask[kb + r] * LOG2E;
      int cb = r >> 3;
#pragma unroll
      for (int rr = 0; rr < 4; ++rr) {
        float pv = __builtin_amdgcn_exp2f(fmaf(s[rr], SC, mvl));
        int prow = quad * 4 + rr;
        Pw[prow * 64 + ((cb ^ (prow & 7)) << 3) + (r & 7)] = f2bf_fast(pv);
      }
    }
    // P: C-layout -> A-operand layout (same-wave LDS roundtrip, no barrier)
    s16x8 ap0 = *(const s16x8*)(Pw + l16 * 64 + ((quad ^ (l16 & 7)) << 3));
    s16x8 ap1 = *(const s16x8*)(Pw + l16 * 64 + (((quad + 4) ^ (l16 & 7)) << 3));
    lacc = __builtin_amdgcn_mfma_f32_16x16x32_bf16(ap0, ones, lacc, 0, 0, 0);
    lacc = __builtin_amdgcn_mfma_f32_16x16x32_bf16(ap1, ones, lacc, 0, 0, 0);
#pragma unroll
    for (int ni = 0; ni < 4; ++ni) {
      const int r = ni * 16 + l16;              // d index
      const short* vr = vt + r * 64;
      s16x8 bv0 = *(const s16x8*)(vr + ((quad ^ (r & 7)) << 3));
      s16x8 bv1 = *(const s16x8*)(vr + (((quad + 4) ^ (r & 7)) << 3));
      o[ni] = __builtin_amdgcn_mfma_f32_16x16x32_bf16(ap0, bv0, o[ni], 0, 0, 0);
      o[ni] = __builtin_amdgcn_mfma_f32_16x16x32_bf16(ap1, bv1, o[ni], 0, 0, 0);
    }
    __syncthreads();   // staging of next tile landed during compute; syncs
                       // buf reuse across waves (single barrier per tile)
  }

#pragma unroll
  for (int rr = 0; rr < 4; ++rr) {
    float inv = 1.0f / lacc[rr];
    int tq = q0 + wave * 16 + quad * 4 + rr;
#pragma unroll
    for (int ni = 0; ni < 4; ++ni)
      AO[(size_t)tq * 1536 + h * 64 + ni * 16 + l16] = f2bf(o[ni][rr] * inv);
  }
}

// ---------------------------------------------------------------------------
extern "C" void kernel_launch(void* const* d_in, const int* in_sizes, int n_in,
                              void* d_out, int out_size, void* d_ws, size_t ws_size,
                              hipStream_t stream) {
  (void)in_sizes; (void)n_in; (void)out_size; (void)ws_size;
  const float* hidden = (const float*)d_in[0];
  const float* enc    = (const float*)d_in[1];
  const float* amask  = (const float*)d_in[2];
  const float* wq  = (const float*)d_in[3];  const float* bq  = (const float*)d_in[4];
  const float* wk  = (const float*)d_in[5];  const float* bk  = (const float*)d_in[6];
  const float* wv  = (const float*)d_in[7];  const float* bv  = (const float*)d_in[8];
  const float* nqw = (const float*)d_in[9];  const float* nkw = (const float*)d_in[10];
  // d_in[11],[12],[17]: add_q_proj + norm_added_q -> dead (context q unused)
  const float* wak = (const float*)d_in[13]; const float* bak = (const float*)d_in[14];
  const float* wav = (const float*)d_in[15]; const float* bav = (const float*)d_in[16];
  const float* nakw = (const float*)d_in[18];
  const float* wo  = (const float*)d_in[19]; const float* bo  = (const float*)d_in[20];
  // d_in[21],[22]: to_add_out -> dead
  float* out = (float*)d_out;

  char* p = (char*)d_ws;
  auto carve = [&](size_t bytes) { char* r = p; p += (bytes + 255) & ~(size_t)255; return r; };
  short* Xb   = (short*)carve((size_t)2048 * 1536 * 2);
  short* Eb   = (short*)carve((size_t)256 * 1536 * 2);
  short* Wqb  = (short*)carve((size_t)1536 * 1536 * 2);
  short* Wkb  = (short*)carve((size_t)1536 * 1536 * 2);
  short* Wvb  = (short*)carve((size_t)1536 * 1536 * 2);
  short* Wakb = (short*)carve((size_t)1536 * 1536 * 2);
  short* Wavb = (short*)carve((size_t)1536 * 1536 * 2);
  short* Wob  = (short*)carve((size_t)1536 * 1536 * 2);
  short* Qb   = (short*)carve((size_t)24 * 2048 * 64 * 2);
  short* Kb   = (short*)carve((size_t)24 * 2304 * 64 * 2);
  short* VTb  = (short*)carve((size_t)24 * 64 * 2304 * 2);
  short* AOb  = (short*)carve((size_t)2048 * 1536 * 2);

  CvtArgs ca;
  ca.s[0] = {hidden, Xb, 2048 * 1536 / 4};
  ca.s[1] = {enc,    Eb, 256 * 1536 / 4};
  ca.s[2] = {wq,  Wqb,  1536 * 1536 / 4};
  ca.s[3] = {wk,  Wkb,  1536 * 1536 / 4};
  ca.s[4] = {wv,  Wvb,  1536 * 1536 / 4};
  ca.s[5] = {wak, Wakb, 1536 * 1536 / 4};
  ca.s[6] = {wav, Wavb, 1536 * 1536 / 4};
  ca.s[7] = {wo,  Wob,  1536 * 1536 / 4};
  cvt_bf16_kernel<<<dim3(1024), dim3(256), 0, stream>>>(ca);

  GemmArgs g1;  // all five projections in one launch (z = 0..4)
  g1.c[0] = {Xb, Wqb,  bq,  nqw,     (void*)Qb,  0,    MODE_Q, 16};
  g1.c[1] = {Xb, Wkb,  bk,  nkw,     (void*)Kb,  0,    MODE_K, 16};
  g1.c[2] = {Xb, Wvb,  bv,  nullptr, (void*)VTb, 0,    MODE_V, 16};
  g1.c[3] = {Eb, Wakb, bak, nakw,    (void*)Kb,  2048, MODE_K, 2};
  g1.c[4] = {Eb, Wavb, bav, nullptr, (void*)VTb, 2048, MODE_V, 2};
  proj_gemm_kernel<<<dim3(12, 16, 5), dim3(256), 0, stream>>>(g1);

  flash_kernel<<<dim3(768), dim3(256), 0, stream>>>(Qb, Kb, VTb, amask, AOb);

  GemmArgs g3;  // out projection -> fp32 d_out
  g3.c[0] = {AOb, Wob, bo, nullptr, (void*)out, 0, MODE_OUT, 16};
  proj_gemm_kernel<<<dim3(12, 16, 1), dim3(256), 0, stream>>>(g3);
}